// Round 4
// baseline (944.534 us; speedup 1.0000x reference)
//
#include <hip/hip_runtime.h>
#include <stdint.h>

#define N_COLS   32768
#define N_ROWS   256
#define N_TASKS  512          // 256 rows x {predictions, targets}
#define B1       2048         // level-1 bins (top 11 bits of key)
#define SHIFT1   21
#define SHIFT2   13           // level-2 bins: bits [20:13]
#define MASK2    255u
#define B2       256
#define SMALL_THR 64u
#define CAP      4096         // max LDS-stageable bucket (expected max ~1900)
#define SC_THR   1024
#define CHUNK    8192
#define NCHUNK   (N_COLS / CHUNK)   // 4

// order-preserving float->uint32 key
__device__ __forceinline__ uint32_t fkey(float x) {
    uint32_t u = __float_as_uint(x);
    return u ^ ((uint32_t)((int32_t)u >> 31) | 0x80000000u);
}

__device__ __forceinline__ const float* task_src(int t, const float* P, const float* Tg) {
    return (t < N_ROWS ? P : Tg) + (size_t)(t & (N_ROWS - 1)) * N_COLS;
}

// 2048-bin exclusive scan with 1024 threads (2 bins/thread). cnt preserved.
// wtot: 16-u32 scratch. Caller must __syncthreads() after return.
__device__ __forceinline__ void scan2048(const uint32_t* cnt, uint32_t* outs, uint32_t* wtot) {
    int tid = threadIdx.x, lane = tid & 63, w = tid >> 6;
    uint32_t a = cnt[2 * tid], b = cnt[2 * tid + 1];
    uint32_t s = a + b, incl = s;
#pragma unroll
    for (int off = 1; off < 64; off <<= 1) {
        uint32_t x = __shfl_up(incl, off, 64);
        if (lane >= off) incl += x;
    }
    if (lane == 63) wtot[w] = incl;
    __syncthreads();
    if (tid == 0) {
        uint32_t run = 0;
        for (int i = 0; i < 16; ++i) { uint32_t t = wtot[i]; wtot[i] = run; run += t; }
    }
    __syncthreads();
    uint32_t excl = incl - s + wtot[w];
    outs[2 * tid]     = excl;
    outs[2 * tid + 1] = excl + a;
}

// ---- K1: fused hist + scan + work-lists + LDS-run-coalesced counting-sort scatter ----
// One block per task. Writes packed 8B (key<<32 | id) records in bucket order (coalesced runs).
__global__ void __launch_bounds__(SC_THR) k_scatter(const float* P, const float* Tg,
                                                    unsigned long long* rec8, uint16_t* bidx,
                                                    uint32_t* cnts,
                                                    unsigned long long* list, unsigned long long* slist) {
    extern __shared__ uint8_t smem[];
    unsigned long long* rec = (unsigned long long*)smem;        // 64 KB staging
    uint32_t* cumg = (uint32_t*)(smem + 65536);                 // 8 KB global cursors
    uint32_t* lh   = (uint32_t*)(smem + 65536 + 8192);          // 8 KB counts
    uint32_t* lst  = (uint32_t*)(smem + 65536 + 16384);         // 8 KB starts/cursors
    uint32_t* wtot = (uint32_t*)(smem + 65536 + 24576);         // 64 B
    int t = blockIdx.x, tid = threadIdx.x;
    const float* src = task_src(t, P, Tg);
    size_t base = (size_t)t << 15;

    // phase 0: full-task hist -> scan -> cursors + large/small lists
    for (int i = tid; i < B1; i += SC_THR) lh[i] = 0;
    __syncthreads();
    for (int j4 = tid; j4 < N_COLS / 4; j4 += SC_THR) {
        float4 v = ((const float4*)src)[j4];
        atomicAdd(&lh[fkey(v.x) >> SHIFT1], 1u);
        atomicAdd(&lh[fkey(v.y) >> SHIFT1], 1u);
        atomicAdd(&lh[fkey(v.z) >> SHIFT1], 1u);
        atomicAdd(&lh[fkey(v.w) >> SHIFT1], 1u);
    }
    __syncthreads();
    scan2048(lh, cumg, wtot);
    __syncthreads();
    for (int b = tid; b < B1; b += SC_THR) {
        uint32_t v = lh[b];
        if (v > SMALL_THR) {
            uint32_t p = atomicAdd(&cnts[0], 1u);
            list[p] = ((unsigned long long)t << 32) | ((unsigned long long)cumg[b] << 16) | v;
        } else if (v) {
            uint32_t p = atomicAdd(&cnts[1], 1u);
            slist[p] = ((unsigned long long)t << 32) | ((unsigned long long)cumg[b] << 16) | v;
        }
    }
    __syncthreads();

    // chunked scatter: local hist -> scan -> LDS scatter -> run-coalesced global write
    for (int c = 0; c < NCHUNK; ++c) {
        for (int i = tid; i < B1; i += SC_THR) lh[i] = 0;
        __syncthreads();
        int j4b = c * (CHUNK / 4) + 2 * tid;        // two consecutive float4 per thread
        float4 va = ((const float4*)src)[j4b];
        float4 vb = ((const float4*)src)[j4b + 1];
        uint32_t k[8];
        k[0] = fkey(va.x); k[1] = fkey(va.y); k[2] = fkey(va.z); k[3] = fkey(va.w);
        k[4] = fkey(vb.x); k[5] = fkey(vb.y); k[6] = fkey(vb.z); k[7] = fkey(vb.w);
#pragma unroll
        for (int r = 0; r < 8; ++r) atomicAdd(&lh[k[r] >> SHIFT1], 1u);
        __syncthreads();
        scan2048(lh, lst, wtot);
        __syncthreads();
        uint32_t id0 = (uint32_t)(j4b * 4);
#pragma unroll
        for (int r = 0; r < 8; ++r) {
            uint32_t b = k[r] >> SHIFT1;
            uint32_t slot = atomicAdd(&lst[b], 1u);
            rec[slot] = ((unsigned long long)k[r] << 32) | (unsigned long long)(id0 + r);
        }
        __syncthreads();
        for (int i = tid; i < CHUNK; i += SC_THR) {
            unsigned long long rr = rec[i];
            uint32_t b  = (uint32_t)(rr >> 53);
            uint32_t st = lst[b] - lh[b];            // post-atomic cursor minus count = start
            uint32_t gp = cumg[b] + ((uint32_t)i - st);
            if (rec8) rec8[base + gp] = rr;
            else      bidx[base + gp] = (uint16_t)(rr & 0xFFFFu);
        }
        __syncthreads();
        for (int b = tid; b < B1; b += SC_THR) cumg[b] += lh[b];
        __syncthreads();
    }
}

// ---- K2: rank large buckets (m > 64) -> write sorted ids (coalesced) ----
__global__ void __launch_bounds__(256) k_large(const float* P, const float* Tg,
                                               const unsigned long long* rec8, const uint16_t* bidx,
                                               uint16_t* sid,
                                               const uint32_t* cnts, const unsigned long long* list) {
    __shared__ uint32_t sk[CAP];
    __shared__ uint16_t si[CAP];
    __shared__ uint32_t sk2[CAP];
    __shared__ uint16_t si2[CAP];
    __shared__ uint32_t sh[B2];
    __shared__ uint32_t stmp[256];
    uint32_t nlist = cnts[0];
    for (uint32_t e = blockIdx.x; e < nlist; e += gridDim.x) {
        unsigned long long ent = list[e];
        uint32_t t     = (uint32_t)(ent >> 32);
        uint32_t start = (uint32_t)(ent >> 16) & 0xFFFFu;
        uint32_t m     = (uint32_t)ent & 0xFFFFu;
        size_t base = (size_t)t << 15;
        const float* src = task_src((int)t, P, Tg);
        if (m <= CAP) {
            if (threadIdx.x < B2) sh[threadIdx.x] = 0;
            for (uint32_t i = threadIdx.x; i < m; i += 256) {
                if (rec8) {
                    unsigned long long rr = rec8[base + start + i];
                    sk[i] = (uint32_t)(rr >> 32); si[i] = (uint16_t)(rr & 0xFFFFu);
                } else {
                    uint16_t id = bidx[base + start + i];
                    sk[i] = fkey(src[id]); si[i] = id;
                }
            }
            __syncthreads();
            for (uint32_t i = threadIdx.x; i < m; i += 256)
                atomicAdd(&sh[(sk[i] >> SHIFT2) & MASK2], 1u);
            __syncthreads();
            { // exclusive scan of sh[0..255]
                uint32_t v = sh[threadIdx.x];
                stmp[threadIdx.x] = v;
                __syncthreads();
                for (int off = 1; off < 256; off <<= 1) {
                    uint32_t x = (threadIdx.x >= (unsigned)off) ? stmp[threadIdx.x - off] : 0u;
                    __syncthreads();
                    stmp[threadIdx.x] += x;
                    __syncthreads();
                }
                sh[threadIdx.x] = stmp[threadIdx.x] - v;
            }
            __syncthreads();
            for (uint32_t i = threadIdx.x; i < m; i += 256) { // LDS sub-scatter by bits [20:13]
                uint32_t kk = sk[i]; uint16_t id = si[i];
                uint32_t pos = atomicAdd(&sh[(kk >> SHIFT2) & MASK2], 1u);
                sk2[pos] = kk; si2[pos] = id;
            }
            __syncthreads();
            for (uint32_t p2 = threadIdx.x; p2 < m; p2 += 256) {
                uint32_t kk = sk2[p2]; uint32_t id = si2[p2];
                uint32_t d2 = (kk >> SHIFT2) & MASK2;
                uint32_t gs = d2 ? sh[d2 - 1] : 0u;   // sh = inclusive ends now
                uint32_t ge = sh[d2];
                uint32_t cnt = 0;
                for (uint32_t q = gs; q < ge; ++q) {
                    uint32_t kq = sk2[q];
                    cnt += (kq < kk || (kq == kk && (uint32_t)si2[q] < id)) ? 1u : 0u;
                }
                sid[base + start + gs + cnt] = (uint16_t)id;
            }
            __syncthreads();
        } else { // safety fallback; statistically unreachable
            for (uint32_t i = threadIdx.x; i < m; i += 256) {
                uint32_t kk, id;
                if (rec8) { unsigned long long rr = rec8[base + start + i]; kk = (uint32_t)(rr >> 32); id = (uint32_t)(rr & 0xFFFFu); }
                else      { id = bidx[base + start + i]; kk = fkey(src[id]); }
                uint32_t cnt = 0;
                for (uint32_t q = 0; q < m; ++q) {
                    uint32_t kq, iq;
                    if (rec8) { unsigned long long rq = rec8[base + start + q]; kq = (uint32_t)(rq >> 32); iq = (uint32_t)(rq & 0xFFFFu); }
                    else      { iq = bidx[base + start + q]; kq = fkey(src[iq]); }
                    cnt += (kq < kk || (kq == kk && iq < id)) ? 1u : 0u;
                }
                sid[base + start + cnt] = (uint16_t)id;
            }
            __syncthreads();
        }
    }
}

// ---- K3: rank small buckets (1..64) — one wave per list entry ----
__global__ void __launch_bounds__(256) k_small(const float* P, const float* Tg,
                                               const unsigned long long* rec8, const uint16_t* bidx,
                                               uint16_t* sid,
                                               const uint32_t* cnts, const unsigned long long* slist) {
    uint32_t gw   = (blockIdx.x * 256u + threadIdx.x) >> 6;
    uint32_t lane = threadIdx.x & 63u;
    uint32_t nw   = (gridDim.x * 256u) >> 6;
    uint32_t nsl  = cnts[1];
    for (uint32_t e = gw; e < nsl; e += nw) {
        unsigned long long ent = slist[e];
        uint32_t t     = (uint32_t)(ent >> 32);
        uint32_t start = (uint32_t)(ent >> 16) & 0xFFFFu;
        uint32_t m     = (uint32_t)ent & 0xFFFFu;
        size_t base = (size_t)t << 15;
        uint32_t id = 0xFFFFFFFFu, k = 0u;
        if (lane < m) {
            if (rec8) { unsigned long long rr = rec8[base + start + lane]; k = (uint32_t)(rr >> 32); id = (uint32_t)(rr & 0xFFFFu); }
            else      { id = bidx[base + start + lane]; k = fkey(task_src((int)t, P, Tg)[id]); }
        }
        uint32_t cnt = 0;
        for (uint32_t q = 0; q < m; ++q) {
            uint32_t kq = __shfl(k, (int)q, 64);
            uint32_t iq = __shfl(id, (int)q, 64);
            cnt += (kq < k || (kq == k && iq < id)) ? 1u : 0u;
        }
        if (lane < m) sid[base + start + cnt] = (uint16_t)id;
    }
}

// ---- K4: per-row dot via LDS inverse permutation (no scattered global traffic) ----
__global__ void __launch_bounds__(1024) k_dot(const uint16_t* sid, double* rowloss) {
    extern __shared__ uint8_t smem[];
    uint16_t* inv = (uint16_t*)smem;    // 64 KB: inverse perm of targets row
    int r = blockIdx.x, tid = threadIdx.x;
    const uint4* t4 = (const uint4*)(sid + ((size_t)(r + N_ROWS) << 15));
    const uint4* p4 = (const uint4*)(sid + ((size_t)r << 15));
    for (int j8 = tid; j8 < N_COLS / 8; j8 += 1024) {
        uint4 v = t4[j8];
        uint32_t j = (uint32_t)j8 * 8u;
        inv[v.x & 0xFFFFu] = (uint16_t)(j + 0); inv[v.x >> 16] = (uint16_t)(j + 1);
        inv[v.y & 0xFFFFu] = (uint16_t)(j + 2); inv[v.y >> 16] = (uint16_t)(j + 3);
        inv[v.z & 0xFFFFu] = (uint16_t)(j + 4); inv[v.z >> 16] = (uint16_t)(j + 5);
        inv[v.w & 0xFFFFu] = (uint16_t)(j + 6); inv[v.w >> 16] = (uint16_t)(j + 7);
    }
    __syncthreads();
    unsigned long long s = 0;
    for (int j8 = tid; j8 < N_COLS / 8; j8 += 1024) {
        uint4 v = p4[j8];
        unsigned long long j = (unsigned long long)j8 * 8u;
        s += (j + 0) * (unsigned long long)inv[v.x & 0xFFFFu];
        s += (j + 1) * (unsigned long long)inv[v.x >> 16];
        s += (j + 2) * (unsigned long long)inv[v.y & 0xFFFFu];
        s += (j + 3) * (unsigned long long)inv[v.y >> 16];
        s += (j + 4) * (unsigned long long)inv[v.z & 0xFFFFu];
        s += (j + 5) * (unsigned long long)inv[v.z >> 16];
        s += (j + 6) * (unsigned long long)inv[v.w & 0xFFFFu];
        s += (j + 7) * (unsigned long long)inv[v.w >> 16];
    }
    for (int off = 32; off; off >>= 1) s += __shfl_down(s, off, 64);
    __shared__ unsigned long long sws[16];
    int w = tid >> 6, lane = tid & 63;
    if (lane == 0) sws[w] = s;
    __syncthreads();
    if (tid == 0) {
        unsigned long long tot = 0;
        for (int i = 0; i < 16; ++i) tot += sws[i];
        double S   = (double)tot;
        double num = S - 32768.0 * 16383.5 * 16383.5;        // S - n*mu^2 (exact)
        double den = 32768.0 * 1073741823.0 / 12.0;          // n(n^2-1)/12
        rowloss[r] = 1.0 - num / (den + 1e-8);
    }
}

// ---- K5: deterministic fixed-order final reduction ----
__global__ void __launch_bounds__(256) k_final(const double* rowloss, float* out) {
    __shared__ double s[256];
    s[threadIdx.x] = rowloss[threadIdx.x];
    __syncthreads();
    for (int off = 128; off; off >>= 1) {
        if ((int)threadIdx.x < off) s[threadIdx.x] += s[threadIdx.x + off];
        __syncthreads();
    }
    if (threadIdx.x == 0) out[0] = (float)(s[0] / 256.0);
}

extern "C" void kernel_launch(void* const* d_in, const int* in_sizes, int n_in,
                              void* d_out, int out_size, void* d_ws, size_t ws_size,
                              hipStream_t stream) {
    const float* P  = (const float*)d_in[0];
    const float* Tg = (const float*)d_in[1];
    float* out = (float*)d_out;
    char* ws = (char*)d_ws;
    const size_t MB = 1024 * 1024;

    uint32_t* cnts = (uint32_t*)ws;                                       // 16 B
    unsigned long long* list  = (unsigned long long*)(ws + 4096);          // ~2 MB max
    unsigned long long* slist = (unsigned long long*)(ws + 4 * MB);        // 8 MB max
    uint16_t* sid    = (uint16_t*)(ws + 12 * MB);                          // 32 MB
    double*   rowloss = (double*)(ws + 44 * MB);                           // 2 KB

    bool use_rec8 = (ws_size >= 174 * MB);
    unsigned long long* rec8 = nullptr;
    uint16_t* bidx = nullptr;
    if (use_rec8) rec8 = (unsigned long long*)(ws + 45 * MB);              // 128 MB
    else          bidx = (uint16_t*)(ws + 45 * MB);                        // 32 MB

    const uint32_t scatter_lds = 65536 + 8192 * 3 + 64;                    // 90176 B
    // Opt-in for >64KB dynamic LDS (CUDA-compat API; harmless no-op if not required).
    (void)hipFuncSetAttribute((const void*)k_scatter,
                              hipFuncAttributeMaxDynamicSharedMemorySize, (int)scatter_lds);
    (void)hipFuncSetAttribute((const void*)k_dot,
                              hipFuncAttributeMaxDynamicSharedMemorySize, 65536);

    hipMemsetAsync(cnts, 0, 16, stream);

    k_scatter<<<N_TASKS, SC_THR, scatter_lds, stream>>>(P, Tg, rec8, bidx, cnts, list, slist);
    k_large  <<<4096, 256, 0, stream>>>(P, Tg, rec8, bidx, sid, cnts, list);
    k_small  <<<4096, 256, 0, stream>>>(P, Tg, rec8, bidx, sid, cnts, slist);
    k_dot    <<<N_ROWS, 1024, 65536, stream>>>(sid, rowloss);
    k_final  <<<1, 256, 0, stream>>>(rowloss, out);
}

// Round 5
// 470.385 us; speedup vs baseline: 2.0080x; 2.0080x over previous
//
#include <hip/hip_runtime.h>
#include <stdint.h>

#define N_COLS   32768
#define N_ROWS   256
#define N_TASKS  512          // 256 rows x {predictions, targets}
#define B1       2048         // level-1 bins (top 11 bits of key)
#define SHIFT1   21
#define SHIFT2   13           // level-2 bins: bits [20:13]
#define MASK2    255u
#define B2       256
#define SMALL_THR 64u
#define CAP      4096         // max LDS-stageable bucket (expected max ~3000)
#define HREP     4            // per-wave histogram/cursor replicas (contention split)
#define HTOT     (B1 * HREP)  // 8192 u32 per task

// order-preserving float->uint32 key
__device__ __forceinline__ uint32_t fkey(float x) {
    uint32_t u = __float_as_uint(x);
    return u ^ ((uint32_t)((int32_t)u >> 31) | 0x80000000u);
}

__device__ __forceinline__ const float* task_src(int t, const float* P, const float* Tg) {
    return (t < N_ROWS ? P : Tg) + (size_t)(t & (N_ROWS - 1)) * N_COLS;
}

// ---- K1: per-task histogram, 4 replicas per bin (measured-good in round 2) ----
// element->replica mapping (512 threads, j4 stride 512, rep=(tid>>6)&3) MUST match k_scatter.
__global__ void __launch_bounds__(512) k_hist(const float* P, const float* Tg, uint32_t* hist) {
    int t = blockIdx.x;
    const float* src = task_src(t, P, Tg);
    __shared__ uint32_t h[HTOT];
    for (int i = threadIdx.x; i < HTOT; i += 512) h[i] = 0;
    __syncthreads();
    int rep = (threadIdx.x >> 6) & 3;
    for (int j4 = threadIdx.x; j4 < N_COLS / 4; j4 += 512) {
        float4 v = ((const float4*)src)[j4];
        atomicAdd(&h[((fkey(v.x) >> SHIFT1) << 2) + rep], 1u);
        atomicAdd(&h[((fkey(v.y) >> SHIFT1) << 2) + rep], 1u);
        atomicAdd(&h[((fkey(v.z) >> SHIFT1) << 2) + rep], 1u);
        atomicAdd(&h[((fkey(v.w) >> SHIFT1) << 2) + rep], 1u);
    }
    __syncthreads();
    uint32_t* o = hist + (size_t)t * HTOT;
    for (int i = threadIdx.x; i < HTOT; i += 512) o[i] = h[i];
}

// ---- K2: per-task exclusive prefix -> per-replica cursors + work lists (round-2 verbatim) ----
__global__ void __launch_bounds__(256) k_scan(uint32_t* hist, uint32_t* cnts,
                                              unsigned long long* list, unsigned long long* slist) {
    int t = blockIdx.x;
    uint4* h4 = (uint4*)(hist + (size_t)t * HTOT);
    __shared__ uint32_t stmp[256];
    uint32_t run = 0;
    for (int c = 0; c < B1 / 256; ++c) {
        int bin = c * 256 + threadIdx.x;
        uint4 hv = h4[bin];
        uint32_t v = hv.x + hv.y + hv.z + hv.w;
        stmp[threadIdx.x] = v;
        __syncthreads();
        for (int off = 1; off < 256; off <<= 1) {
            uint32_t x = (threadIdx.x >= (unsigned)off) ? stmp[threadIdx.x - off] : 0u;
            __syncthreads();
            stmp[threadIdx.x] += x;
            __syncthreads();
        }
        uint32_t incl = stmp[threadIdx.x];
        uint32_t tot  = stmp[255];
        uint32_t start = run + incl - v;     // task-local exclusive prefix (bucket start)
        if (v > SMALL_THR) {
            uint32_t p = atomicAdd(&cnts[0], 1u);
            list[p] = ((unsigned long long)t << 32) | ((unsigned long long)start << 16) | v;
        } else if (v) {
            uint32_t p = atomicAdd(&cnts[1], 1u);
            slist[p] = ((unsigned long long)t << 32) | ((unsigned long long)start << 16) | v;
        }
        uint4 w;                              // per-replica cursor starts
        w.x = start;
        w.y = w.x + hv.x;
        w.z = w.y + hv.y;
        w.w = w.z + hv.z;
        h4[bin] = w;
        run += tot;
        __syncthreads();
    }
}

// ---- K3: counting-sort scatter, LDS cursors, ONE packed 8B store per element ----
__global__ void __launch_bounds__(512) k_scatter(const float* P, const float* Tg, const uint32_t* hist,
                                                 unsigned long long* rec8, uint16_t* bidx) {
    int t = blockIdx.x;
    const float* src = task_src(t, P, Tg);
    const uint32_t* h = hist + (size_t)t * HTOT;
    __shared__ uint32_t sc[HTOT];
    for (int i = threadIdx.x; i < HTOT; i += 512) sc[i] = h[i];
    __syncthreads();
    int rep = (threadIdx.x >> 6) & 3;         // must match k_hist
    size_t base = (size_t)t << 15;
    for (int j4 = threadIdx.x; j4 < N_COLS / 4; j4 += 512) {
        float4 v = ((const float4*)src)[j4];
        float xs[4] = {v.x, v.y, v.z, v.w};
#pragma unroll
        for (int c = 0; c < 4; ++c) {
            uint32_t k = fkey(xs[c]);
            uint32_t pos = atomicAdd(&sc[((k >> SHIFT1) << 2) + rep], 1u);
            if (rec8) rec8[base + pos] = ((unsigned long long)k << 32) | (unsigned long long)(j4 * 4 + c);
            else      bidx[base + pos] = (uint16_t)(j4 * 4 + c);
        }
    }
}

// ---- K4: rank large buckets (m > 64) -> write sorted ids (coalesced) ----
__global__ void __launch_bounds__(256) k_large(const float* P, const float* Tg,
                                               const unsigned long long* rec8, const uint16_t* bidx,
                                               uint16_t* sid,
                                               const uint32_t* cnts, const unsigned long long* list) {
    __shared__ uint32_t sk[CAP];
    __shared__ uint16_t si[CAP];
    __shared__ uint32_t sk2[CAP];
    __shared__ uint16_t si2[CAP];
    __shared__ uint32_t sh[B2];
    __shared__ uint32_t stmp[256];
    uint32_t nlist = cnts[0];
    for (uint32_t e = blockIdx.x; e < nlist; e += gridDim.x) {
        unsigned long long ent = list[e];
        uint32_t t     = (uint32_t)(ent >> 32);
        uint32_t start = (uint32_t)(ent >> 16) & 0xFFFFu;
        uint32_t m     = (uint32_t)ent & 0xFFFFu;
        size_t base = (size_t)t << 15;
        const float* src = task_src((int)t, P, Tg);
        if (m <= CAP) {
            if (threadIdx.x < B2) sh[threadIdx.x] = 0;
            for (uint32_t i = threadIdx.x; i < m; i += 256) {
                if (rec8) {
                    unsigned long long rr = rec8[base + start + i];
                    sk[i] = (uint32_t)(rr >> 32); si[i] = (uint16_t)(rr & 0xFFFFu);
                } else {
                    uint16_t id = bidx[base + start + i];
                    sk[i] = fkey(src[id]); si[i] = id;
                }
            }
            __syncthreads();
            for (uint32_t i = threadIdx.x; i < m; i += 256)
                atomicAdd(&sh[(sk[i] >> SHIFT2) & MASK2], 1u);
            __syncthreads();
            { // exclusive scan of sh[0..255]
                uint32_t v = sh[threadIdx.x];
                stmp[threadIdx.x] = v;
                __syncthreads();
                for (int off = 1; off < 256; off <<= 1) {
                    uint32_t x = (threadIdx.x >= (unsigned)off) ? stmp[threadIdx.x - off] : 0u;
                    __syncthreads();
                    stmp[threadIdx.x] += x;
                    __syncthreads();
                }
                sh[threadIdx.x] = stmp[threadIdx.x] - v;
            }
            __syncthreads();
            for (uint32_t i = threadIdx.x; i < m; i += 256) { // LDS sub-scatter by bits [20:13]
                uint32_t kk = sk[i]; uint16_t id = si[i];
                uint32_t pos = atomicAdd(&sh[(kk >> SHIFT2) & MASK2], 1u);
                sk2[pos] = kk; si2[pos] = id;
            }
            __syncthreads();
            for (uint32_t p2 = threadIdx.x; p2 < m; p2 += 256) {
                uint32_t kk = sk2[p2]; uint32_t id = si2[p2];
                uint32_t d2 = (kk >> SHIFT2) & MASK2;
                uint32_t gs = d2 ? sh[d2 - 1] : 0u;   // sh = inclusive ends now
                uint32_t ge = sh[d2];
                uint32_t cnt = 0;
                for (uint32_t q = gs; q < ge; ++q) {
                    uint32_t kq = sk2[q];
                    cnt += (kq < kk || (kq == kk && (uint32_t)si2[q] < id)) ? 1u : 0u;
                }
                sid[base + start + gs + cnt] = (uint16_t)id;
            }
            __syncthreads();
        } else { // safety fallback; statistically unreachable
            for (uint32_t i = threadIdx.x; i < m; i += 256) {
                uint32_t kk, id;
                if (rec8) { unsigned long long rr = rec8[base + start + i]; kk = (uint32_t)(rr >> 32); id = (uint32_t)(rr & 0xFFFFu); }
                else      { id = bidx[base + start + i]; kk = fkey(src[id]); }
                uint32_t cnt = 0;
                for (uint32_t q = 0; q < m; ++q) {
                    uint32_t kq, iq;
                    if (rec8) { unsigned long long rq = rec8[base + start + q]; kq = (uint32_t)(rq >> 32); iq = (uint32_t)(rq & 0xFFFFu); }
                    else      { iq = bidx[base + start + q]; kq = fkey(src[iq]); }
                    cnt += (kq < kk || (kq == kk && iq < id)) ? 1u : 0u;
                }
                sid[base + start + cnt] = (uint16_t)id;
            }
            __syncthreads();
        }
    }
}

// ---- K5: rank small buckets (1..64) — one wave per list entry ----
__global__ void __launch_bounds__(256) k_small(const float* P, const float* Tg,
                                               const unsigned long long* rec8, const uint16_t* bidx,
                                               uint16_t* sid,
                                               const uint32_t* cnts, const unsigned long long* slist) {
    uint32_t gw   = (blockIdx.x * 256u + threadIdx.x) >> 6;
    uint32_t lane = threadIdx.x & 63u;
    uint32_t nw   = (gridDim.x * 256u) >> 6;
    uint32_t nsl  = cnts[1];
    for (uint32_t e = gw; e < nsl; e += nw) {
        unsigned long long ent = slist[e];
        uint32_t t     = (uint32_t)(ent >> 32);
        uint32_t start = (uint32_t)(ent >> 16) & 0xFFFFu;
        uint32_t m     = (uint32_t)ent & 0xFFFFu;
        size_t base = (size_t)t << 15;
        uint32_t id = 0xFFFFFFFFu, k = 0u;
        if (lane < m) {
            if (rec8) { unsigned long long rr = rec8[base + start + lane]; k = (uint32_t)(rr >> 32); id = (uint32_t)(rr & 0xFFFFu); }
            else      { id = bidx[base + start + lane]; k = fkey(task_src((int)t, P, Tg)[id]); }
        }
        uint32_t cnt = 0;
        for (uint32_t q = 0; q < m; ++q) {
            uint32_t kq = __shfl(k, (int)q, 64);
            uint32_t iq = __shfl(id, (int)q, 64);
            cnt += (kq < k || (kq == k && iq < id)) ? 1u : 0u;
        }
        if (lane < m) sid[base + start + cnt] = (uint16_t)id;
    }
}

// ---- K6: per-row dot via LDS inverse permutation (no scattered global traffic) ----
__global__ void __launch_bounds__(1024) k_dot(const uint16_t* sid, double* rowloss) {
    extern __shared__ uint8_t smem[];
    uint16_t* inv = (uint16_t*)smem;    // 64 KB: inverse perm of targets row
    int r = blockIdx.x, tid = threadIdx.x;
    const uint4* t4 = (const uint4*)(sid + ((size_t)(r + N_ROWS) << 15));
    const uint4* p4 = (const uint4*)(sid + ((size_t)r << 15));
    for (int j8 = tid; j8 < N_COLS / 8; j8 += 1024) {
        uint4 v = t4[j8];
        uint32_t j = (uint32_t)j8 * 8u;
        inv[v.x & 0xFFFFu] = (uint16_t)(j + 0); inv[v.x >> 16] = (uint16_t)(j + 1);
        inv[v.y & 0xFFFFu] = (uint16_t)(j + 2); inv[v.y >> 16] = (uint16_t)(j + 3);
        inv[v.z & 0xFFFFu] = (uint16_t)(j + 4); inv[v.z >> 16] = (uint16_t)(j + 5);
        inv[v.w & 0xFFFFu] = (uint16_t)(j + 6); inv[v.w >> 16] = (uint16_t)(j + 7);
    }
    __syncthreads();
    unsigned long long s = 0;
    for (int j8 = tid; j8 < N_COLS / 8; j8 += 1024) {
        uint4 v = p4[j8];
        unsigned long long j = (unsigned long long)j8 * 8u;
        s += (j + 0) * (unsigned long long)inv[v.x & 0xFFFFu];
        s += (j + 1) * (unsigned long long)inv[v.x >> 16];
        s += (j + 2) * (unsigned long long)inv[v.y & 0xFFFFu];
        s += (j + 3) * (unsigned long long)inv[v.y >> 16];
        s += (j + 4) * (unsigned long long)inv[v.z & 0xFFFFu];
        s += (j + 5) * (unsigned long long)inv[v.z >> 16];
        s += (j + 6) * (unsigned long long)inv[v.w & 0xFFFFu];
        s += (j + 7) * (unsigned long long)inv[v.w >> 16];
    }
    for (int off = 32; off; off >>= 1) s += __shfl_down(s, off, 64);
    __shared__ unsigned long long sws[16];
    int w = tid >> 6, lane = tid & 63;
    if (lane == 0) sws[w] = s;
    __syncthreads();
    if (tid == 0) {
        unsigned long long tot = 0;
        for (int i = 0; i < 16; ++i) tot += sws[i];
        double S   = (double)tot;
        double num = S - 32768.0 * 16383.5 * 16383.5;        // S - n*mu^2 (exact)
        double den = 32768.0 * 1073741823.0 / 12.0;          // n(n^2-1)/12
        rowloss[r] = 1.0 - num / (den + 1e-8);
    }
}

// ---- K7: deterministic fixed-order final reduction ----
__global__ void __launch_bounds__(256) k_final(const double* rowloss, float* out) {
    __shared__ double s[256];
    s[threadIdx.x] = rowloss[threadIdx.x];
    __syncthreads();
    for (int off = 128; off; off >>= 1) {
        if ((int)threadIdx.x < off) s[threadIdx.x] += s[threadIdx.x + off];
        __syncthreads();
    }
    if (threadIdx.x == 0) out[0] = (float)(s[0] / 256.0);
}

extern "C" void kernel_launch(void* const* d_in, const int* in_sizes, int n_in,
                              void* d_out, int out_size, void* d_ws, size_t ws_size,
                              hipStream_t stream) {
    const float* P  = (const float*)d_in[0];
    const float* Tg = (const float*)d_in[1];
    float* out = (float*)d_out;
    char* ws = (char*)d_ws;
    const size_t MB = 1024 * 1024;

    uint32_t* hist = (uint32_t*)(ws);                                      // 16 MB (512 x 8192 u32)
    uint32_t* cnts = (uint32_t*)(ws + 16 * MB);                            // 16 B
    unsigned long long* list  = (unsigned long long*)(ws + 16 * MB + 4096); // ~2 MB max
    unsigned long long* slist = (unsigned long long*)(ws + 19 * MB);       // 8 MB max
    uint16_t* sid     = (uint16_t*)(ws + 27 * MB);                         // 32 MB
    double*   rowloss = (double*)(ws + 59 * MB);                           // 2 KB

    bool use_rec8 = (ws_size >= 189 * MB);
    unsigned long long* rec8 = nullptr;
    uint16_t* bidx = nullptr;
    if (use_rec8) rec8 = (unsigned long long*)(ws + 60 * MB);              // 128 MB
    else          bidx = (uint16_t*)(ws + 60 * MB);                        // 32 MB

    (void)hipFuncSetAttribute((const void*)k_dot,
                              hipFuncAttributeMaxDynamicSharedMemorySize, 65536);

    hipMemsetAsync(cnts, 0, 16, stream);

    k_hist   <<<N_TASKS, 512, 0, stream>>>(P, Tg, hist);
    k_scan   <<<N_TASKS, 256, 0, stream>>>(hist, cnts, list, slist);
    k_scatter<<<N_TASKS, 512, 0, stream>>>(P, Tg, hist, rec8, bidx);
    k_large  <<<4096, 256, 0, stream>>>(P, Tg, rec8, bidx, sid, cnts, list);
    k_small  <<<4096, 256, 0, stream>>>(P, Tg, rec8, bidx, sid, cnts, slist);
    k_dot    <<<N_ROWS, 1024, 65536, stream>>>(sid, rowloss);
    k_final  <<<1, 256, 0, stream>>>(rowloss, out);
}